// Round 1
// baseline (269.446 us; speedup 1.0000x reference)
//
#include <hip/hip_runtime.h>

typedef __bf16 bf16x8 __attribute__((ext_vector_type(8)));
typedef __bf16 bf16x4 __attribute__((ext_vector_type(4)));
typedef float f32x4 __attribute__((ext_vector_type(4)));

#define GLOAD_LDS16(g, l)                                                      \
  __builtin_amdgcn_global_load_lds(                                            \
      (const __attribute__((address_space(1))) void*)(g),                      \
      (__attribute__((address_space(3))) void*)(l), 16, 0, 0)

// ---------------- K0: zero the label histogram ----------------
__global__ void k_init(int* __restrict__ cntv) {
  if (threadIdx.x < 4) cntv[threadIdx.x] = 0;
}

// ---------------- K1: normalize rows -> bf16, build code[] + histogram ------
__global__ __launch_bounds__(128) void k_normalize(
    const float* __restrict__ X, const int* __restrict__ labels,
    const int* __restrict__ bad, __bf16* __restrict__ fn,
    unsigned char* __restrict__ code, int* __restrict__ cntv, int Dv) {
  const int row = blockIdx.x;
  const int t = threadIdx.x;
  const float4* xr = (const float4*)(X + (size_t)row * Dv);
  float ss = 0.f;
  const int nv4 = Dv >> 2;
  for (int idx = t; idx < nv4; idx += 128) {
    float4 v = xr[idx];
    ss += v.x * v.x + v.y * v.y + v.z * v.z + v.w * v.w;
  }
#pragma unroll
  for (int off = 32; off; off >>= 1) ss += __shfl_down(ss, off);
  __shared__ float sred[2];
  if ((t & 63) == 0) sred[t >> 6] = ss;
  __syncthreads();
  const float inv = 1.0f / sqrtf(sred[0] + sred[1]);
  for (int idx = t; idx < nv4; idx += 128) {
    float4 v = xr[idx];
    bf16x4 o;
    o.x = (__bf16)(v.x * inv);
    o.y = (__bf16)(v.y * inv);
    o.z = (__bf16)(v.z * inv);
    o.w = (__bf16)(v.w * inv);
    *(bf16x4*)(fn + (size_t)row * Dv + idx * 4) = o;
  }
  if (t == 0) {
    const bool valid = (bad[row] == 0);
    unsigned char c = valid ? (unsigned char)labels[row] : (unsigned char)255;
    code[row] = c;
    if (valid) atomicAdd(&cntv[c], 1);
  }
}

// ---------------- K2: S = (fn . fn^T) * 10, fp16 out -------------------------
// 128x128 tile, BK=32, 4 waves each 64x64 via 4x4 of 16x16x32 bf16 MFMA.
__global__ __launch_bounds__(256) void k_gemm(const __bf16* __restrict__ fn,
                                              _Float16* __restrict__ S, int Nv,
                                              int Dv) {
  __shared__ __align__(16) __bf16 As[128 * 32];
  __shared__ __align__(16) __bf16 Bs[128 * 32];
  const int t = threadIdx.x;
  const int lane = t & 63;
  const int wave = t >> 6;
  const int quad = lane >> 4;
  const int l16 = lane & 15;
  const int wm = (wave >> 1) * 64;
  const int wn = (wave & 1) * 64;
  const size_t rowA = (size_t)blockIdx.x * 128;
  const size_t rowB = (size_t)blockIdx.y * 128;
  f32x4 acc[4][4] = {};

  for (int k0 = 0; k0 < Dv; k0 += 32) {
#pragma unroll
    for (int it = 0; it < 2; ++it) {
      const int c = t + it * 256;  // chunk 0..511 ; chunk = 16B = 8 bf16
      const int r = c >> 2;
      const int q = c & 3;
      const __bf16* ga = fn + (rowA + r) * Dv + k0 + q * 8;
      const __bf16* gb = fn + (rowB + r) * Dv + k0 + q * 8;
      // LDS dest is wave-uniform base + lane*16 (HW behavior)
      __bf16* la = As + (size_t)(it * 256 + wave * 64) * 8;
      __bf16* lb = Bs + (size_t)(it * 256 + wave * 64) * 8;
      GLOAD_LDS16(ga, la);
      GLOAD_LDS16(gb, lb);
    }
    __syncthreads();
    bf16x8 af[4], bf[4];
#pragma unroll
    for (int mi = 0; mi < 4; ++mi)
      af[mi] = *(const bf16x8*)(As + (wm + mi * 16 + l16) * 32 + quad * 8);
#pragma unroll
    for (int ni = 0; ni < 4; ++ni)
      bf[ni] = *(const bf16x8*)(Bs + (wn + ni * 16 + l16) * 32 + quad * 8);
#pragma unroll
    for (int mi = 0; mi < 4; ++mi)
#pragma unroll
      for (int ni = 0; ni < 4; ++ni)
        acc[mi][ni] = __builtin_amdgcn_mfma_f32_16x16x32_bf16(
            af[mi], bf[ni], acc[mi][ni], 0, 0, 0);
    __syncthreads();
  }
  // C/D layout (verified m89/m91): col = lane&15, row = quad*4 + reg
#pragma unroll
  for (int mi = 0; mi < 4; ++mi) {
#pragma unroll
    for (int ni = 0; ni < 4; ++ni) {
#pragma unroll
      for (int r = 0; r < 4; ++r) {
        const size_t grow = rowA + wm + mi * 16 + quad * 4 + r;
        const size_t gcol = rowB + wn + ni * 16 + l16;
        S[grow * Nv + gcol] = (_Float16)(acc[mi][ni][r] * 10.0f);
      }
    }
  }
}

// ---------------- K3: per-row reductions ------------------------------------
__global__ __launch_bounds__(256) void k_rows(
    const _Float16* __restrict__ S, const unsigned char* __restrict__ code,
    const int* __restrict__ cntv, float* __restrict__ pa,
    int* __restrict__ pflag, int Nv) {
  const int i = blockIdx.x;
  const int t = threadIdx.x;
  const int myc = code[i];
  const int c0 = cntv[0], c1 = cntv[1], c2 = cntv[2];
  const int validTotal = c0 + c1 + c2;
  if (myc > 2) {  // invalid anchor: not processed
    if (t == 0) { pa[i] = 0.f; pflag[i] = 0; }
    return;
  }
  const int cmy = (myc == 0) ? c0 : ((myc == 1) ? c1 : c2);
  if (validTotal - cmy == 0) {  // no negatives anywhere: not processed
    if (t == 0) { pa[i] = 0.f; pflag[i] = 0; }
    return;
  }
  __shared__ __align__(16) _Float16 srow[8192];
  __shared__ __align__(16) unsigned char scode[8192];
  __shared__ float red[8];
  {
    const float4* rp = (const float4*)(S + (size_t)i * Nv);
    float4* sp = (float4*)srow;
    for (int idx = t; idx < (Nv >> 3); idx += 256) sp[idx] = rp[idx];
    const float4* cp = (const float4*)code;
    float4* scp = (float4*)scode;
    for (int idx = t; idx < (Nv >> 4); idx += 256) scp[idx] = cp[idx];
  }
  __syncthreads();
  // pass 1: online logsumexp over negatives (valid & different label)
  float m = -1e30f, s = 0.f;
  for (int j = t; j < Nv; j += 256) {
    const int cj = scode[j];
    if (cj <= 2 && cj != myc) {
      const float x = (float)srow[j];
      if (x <= m) {
        s += __expf(x - m);
      } else {
        s = s * __expf(m - x) + 1.f;
        m = x;
      }
    }
  }
#pragma unroll
  for (int off = 32; off; off >>= 1) {
    const float mo = __shfl_down(m, off);
    const float so = __shfl_down(s, off);
    const float M = fmaxf(m, mo);
    s = s * __expf(m - M) + so * __expf(mo - M);
    m = M;
  }
  if ((t & 63) == 0) {
    red[(t >> 6) * 2] = m;
    red[(t >> 6) * 2 + 1] = s;
  }
  __syncthreads();
  float neg_lse;
  {
    const float M =
        fmaxf(fmaxf(red[0], red[2]), fmaxf(red[4], red[6]));
    const float ss = red[1] * __expf(red[0] - M) + red[3] * __expf(red[2] - M) +
                     red[5] * __expf(red[4] - M) + red[7] * __expf(red[6] - M);
    neg_lse = M + __logf(ss);
  }
  // pass 2: sum over positives of log1p(exp(neg_lse - S_ip))
  float psum = 0.f;
  for (int j = t; j < Nv; j += 256) {
    if (scode[j] == myc && j != i) {
      const float x = (float)srow[j];
      psum += __logf(1.f + __expf(neg_lse - x));
    }
  }
#pragma unroll
  for (int off = 32; off; off >>= 1) psum += __shfl_down(psum, off);
  __syncthreads();
  if ((t & 63) == 0) red[t >> 6] = psum;
  __syncthreads();
  if (t == 0) {
    const float tot = red[0] + red[1] + red[2] + red[3];
    const int pos_cnt = cmy - 1;  // self is valid & same label
    float v;
    int fl;
    if (pos_cnt > 0) {
      v = tot / (float)pos_cnt;
      fl = 1;
    } else {
      v = __logf(1.f + __expf(neg_lse - 10.0f));  // logaddexp(1/T, lse) - 1/T
      fl = 0;
    }
    pa[i] = v;
    pflag[i] = fl;
  }
}

// ---------------- K4: final deterministic reduce ----------------------------
__global__ __launch_bounds__(256) void k_final(const float* __restrict__ pa,
                                               const int* __restrict__ pflag,
                                               float* __restrict__ out,
                                               int Nv) {
  const int t = threadIdx.x;
  double s = 0.0;
  int c = 0;
  for (int j = t; j < Nv; j += 256) {
    s += (double)pa[j];
    c += pflag[j];
  }
#pragma unroll
  for (int off = 32; off; off >>= 1) {
    s += __shfl_down(s, off);
    c += __shfl_down(c, off);
  }
  __shared__ double sd[4];
  __shared__ int si[4];
  if ((t & 63) == 0) {
    sd[t >> 6] = s;
    si[t >> 6] = c;
  }
  __syncthreads();
  if (t == 0) {
    const double st = sd[0] + sd[1] + sd[2] + sd[3];
    const int ct = 1 + si[0] + si[1] + si[2] + si[3];
    out[0] = (float)(st / (double)ct);
  }
}

extern "C" void kernel_launch(void* const* d_in, const int* in_sizes, int n_in,
                              void* d_out, int out_size, void* d_ws,
                              size_t ws_size, hipStream_t stream) {
  const float* X = (const float*)d_in[0];
  const int* labels = (const int*)d_in[1];
  const int* bad = (const int*)d_in[2];
  const int Nv = in_sizes[1];
  const int Dv = in_sizes[0] / Nv;

  size_t off = 0;
  auto alloc = [&](size_t bytes) -> void* {
    size_t p = (off + 255) & ~(size_t)255;
    off = p + bytes;
    return (void*)((char*)d_ws + p);
  };
  __bf16* fn = (__bf16*)alloc((size_t)Nv * Dv * 2);
  _Float16* S = (_Float16*)alloc((size_t)Nv * Nv * 2);
  float* pa = (float*)alloc((size_t)Nv * 4);
  int* pflag = (int*)alloc((size_t)Nv * 4);
  unsigned char* code = (unsigned char*)alloc((size_t)Nv);
  int* cntv = (int*)alloc(16);
  if (off > ws_size) return;  // scratch too small: fail loudly at validation

  k_init<<<1, 64, 0, stream>>>(cntv);
  k_normalize<<<Nv, 128, 0, stream>>>(X, labels, bad, fn, code, cntv, Dv);
  dim3 g(Nv / 128, Nv / 128);
  k_gemm<<<g, 256, 0, stream>>>(fn, S, Nv, Dv);
  k_rows<<<Nv, 256, 0, stream>>>(S, code, cntv, pa, pflag, Nv);
  k_final<<<1, 256, 0, stream>>>(pa, pflag, (float*)d_out, Nv);
}

// Round 2
// 267.343 us; speedup vs baseline: 1.0079x; 1.0079x over previous
//
#include <hip/hip_runtime.h>

typedef __bf16 bf16x8 __attribute__((ext_vector_type(8)));
typedef __bf16 bf16x4 __attribute__((ext_vector_type(4)));
typedef float f32x4 __attribute__((ext_vector_type(4)));

#define GLOAD_LDS16(g, l)                                                      \
  __builtin_amdgcn_global_load_lds(                                            \
      (const __attribute__((address_space(1))) void*)(g),                      \
      (__attribute__((address_space(3))) void*)(l), 16, 0, 0)

// ---------------- K0: zero the label histogram ----------------
__global__ void k_init(int* __restrict__ cntv) {
  if (threadIdx.x < 4) cntv[threadIdx.x] = 0;
}

// ---------------- K1: normalize rows -> bf16, build code[] + histogram ------
__global__ __launch_bounds__(128) void k_normalize(
    const float* __restrict__ X, const int* __restrict__ labels,
    const int* __restrict__ bad, __bf16* __restrict__ fn,
    unsigned char* __restrict__ code, int* __restrict__ cntv, int Dv) {
  const int row = blockIdx.x;
  const int t = threadIdx.x;
  const float4* xr = (const float4*)(X + (size_t)row * Dv);
  float ss = 0.f;
  const int nv4 = Dv >> 2;
  for (int idx = t; idx < nv4; idx += 128) {
    float4 v = xr[idx];
    ss += v.x * v.x + v.y * v.y + v.z * v.z + v.w * v.w;
  }
#pragma unroll
  for (int off = 32; off; off >>= 1) ss += __shfl_down(ss, off);
  __shared__ float sred[2];
  if ((t & 63) == 0) sred[t >> 6] = ss;
  __syncthreads();
  const float inv = 1.0f / sqrtf(sred[0] + sred[1]);
  for (int idx = t; idx < nv4; idx += 128) {
    float4 v = xr[idx];
    bf16x4 o;
    o.x = (__bf16)(v.x * inv);
    o.y = (__bf16)(v.y * inv);
    o.z = (__bf16)(v.z * inv);
    o.w = (__bf16)(v.w * inv);
    *(bf16x4*)(fn + (size_t)row * Dv + idx * 4) = o;
  }
  if (t == 0) {
    const bool valid = (bad[row] == 0);
    unsigned char c = valid ? (unsigned char)labels[row] : (unsigned char)255;
    code[row] = c;
    if (valid) atomicAdd(&cntv[c], 1);
  }
}

// ---------------- K2: S = (fn . fn^T) * 10, fp16 out -------------------------
// 128x128 tile, BK=64, 4 waves each 64x64 via 4x4 of 16x16x32 bf16 MFMA.
// Epilogue stages C through LDS (union with A/B bufs) for coalesced stores.
__global__ __launch_bounds__(256) void k_gemm(const __bf16* __restrict__ fn,
                                              _Float16* __restrict__ S, int Nv,
                                              int Dv) {
  __shared__ __align__(16) char smem[34816];  // max(2*16384, 128*136*2)
  __bf16* As = (__bf16*)smem;                 // 128 x 64 bf16
  __bf16* Bs = (__bf16*)(smem + 16384);       // 128 x 64 bf16
  _Float16* Cs = (_Float16*)smem;             // 128 x 136 fp16 (epilogue)

  const int t = threadIdx.x;
  const int lane = t & 63;
  const int wave = t >> 6;
  const int quad = lane >> 4;
  const int l16 = lane & 15;
  const int wm = (wave >> 1) * 64;
  const int wn = (wave & 1) * 64;
  const size_t rowA = (size_t)blockIdx.x * 128;
  const size_t rowB = (size_t)blockIdx.y * 128;
  f32x4 acc[4][4] = {};

  for (int k0 = 0; k0 < Dv; k0 += 64) {
#pragma unroll
    for (int it = 0; it < 4; ++it) {
      const int c = t + it * 256;  // chunk 0..1023 ; chunk = 16B = 8 bf16
      const int r = c >> 3;
      const int q = c & 7;
      const __bf16* ga = fn + (rowA + r) * Dv + k0 + q * 8;
      const __bf16* gb = fn + (rowB + r) * Dv + k0 + q * 8;
      // LDS dest is wave-uniform base + lane*16 (HW behavior)
      __bf16* la = As + (size_t)(it * 256 + wave * 64) * 8;
      __bf16* lb = Bs + (size_t)(it * 256 + wave * 64) * 8;
      GLOAD_LDS16(ga, la);
      GLOAD_LDS16(gb, lb);
    }
    __syncthreads();
#pragma unroll
    for (int kk = 0; kk < 2; ++kk) {
      bf16x8 af[4], bfv[4];
#pragma unroll
      for (int mi = 0; mi < 4; ++mi)
        af[mi] =
            *(const bf16x8*)(As + (wm + mi * 16 + l16) * 64 + kk * 32 + quad * 8);
#pragma unroll
      for (int ni = 0; ni < 4; ++ni)
        bfv[ni] =
            *(const bf16x8*)(Bs + (wn + ni * 16 + l16) * 64 + kk * 32 + quad * 8);
#pragma unroll
      for (int mi = 0; mi < 4; ++mi)
#pragma unroll
        for (int ni = 0; ni < 4; ++ni)
          acc[mi][ni] = __builtin_amdgcn_mfma_f32_16x16x32_bf16(
              af[mi], bfv[ni], acc[mi][ni], 0, 0, 0);
    }
    __syncthreads();
  }
  // C/D layout (verified m89/m91): col = lane&15, row = quad*4 + reg
  // Stage to LDS fp16 (stride 136 -> 272B rows, 16B aligned), then coalesced
  // float4 stores.
#pragma unroll
  for (int mi = 0; mi < 4; ++mi)
#pragma unroll
    for (int ni = 0; ni < 4; ++ni)
#pragma unroll
      for (int r = 0; r < 4; ++r)
        Cs[(wm + mi * 16 + quad * 4 + r) * 136 + wn + ni * 16 + l16] =
            (_Float16)(acc[mi][ni][r] * 10.0f);
  __syncthreads();
#pragma unroll
  for (int it = 0; it < 8; ++it) {
    const int idx = t + it * 256;  // 0..2047: row*16 + 16B-chunk
    const int row = idx >> 4;
    const int ch = idx & 15;
    *(float4*)(S + (rowA + row) * Nv + rowB + ch * 8) =
        *(const float4*)(Cs + row * 136 + ch * 8);
  }
}

// ---------------- K3: per-row reductions ------------------------------------
__global__ __launch_bounds__(256) void k_rows(
    const _Float16* __restrict__ S, const unsigned char* __restrict__ code,
    const int* __restrict__ cntv, float* __restrict__ pa,
    int* __restrict__ pflag, int Nv) {
  const int i = blockIdx.x;
  const int t = threadIdx.x;
  const int myc = code[i];
  const int c0 = cntv[0], c1 = cntv[1], c2 = cntv[2];
  const int validTotal = c0 + c1 + c2;
  if (myc > 2) {  // invalid anchor: not processed
    if (t == 0) { pa[i] = 0.f; pflag[i] = 0; }
    return;
  }
  const int cmy = (myc == 0) ? c0 : ((myc == 1) ? c1 : c2);
  if (validTotal - cmy == 0) {  // no negatives anywhere: not processed
    if (t == 0) { pa[i] = 0.f; pflag[i] = 0; }
    return;
  }
  __shared__ __align__(16) _Float16 srow[8192];
  __shared__ __align__(16) unsigned char scode[8192];
  __shared__ float red[4];
  __shared__ float sE;
  {
    const float4* rp = (const float4*)(S + (size_t)i * Nv);
    float4* sp = (float4*)srow;
    for (int idx = t; idx < (Nv >> 3); idx += 256) sp[idx] = rp[idx];
    const float4* cp = (const float4*)code;
    float4* scp = (float4*)scode;
    for (int idx = t; idx < (Nv >> 4); idx += 256) scp[idx] = cp[idx];
  }
  __syncthreads();
  // pass 1: E = sum over negatives of exp(S_ij). |S|<=~10 so no overflow:
  // max sum ~ 8192*e^10 ~ 1.8e8, safely inside fp32.
  float s = 0.f;
  for (int j8 = t; j8 < (Nv >> 3); j8 += 256) {
    const float4 rv = *(const float4*)(srow + j8 * 8);
    const uint2 cv = *(const uint2*)(scode + j8 * 8);
    const _Float16* hp = (const _Float16*)&rv;
    const unsigned char* cb = (const unsigned char*)&cv;
#pragma unroll
    for (int k = 0; k < 8; ++k) {
      const int cj = cb[k];
      const float e = __expf((float)hp[k]);
      s += (cj <= 2 && cj != myc) ? e : 0.f;
    }
  }
#pragma unroll
  for (int off = 32; off; off >>= 1) s += __shfl_down(s, off);
  if ((t & 63) == 0) red[t >> 6] = s;
  __syncthreads();
  if (t == 0) sE = red[0] + red[1] + red[2] + red[3];
  __syncthreads();
  const float E = sE;
  // pass 2: sum over positives of log1p(E * exp(-S_ij))
  float psum = 0.f;
  for (int j8 = t; j8 < (Nv >> 3); j8 += 256) {
    const float4 rv = *(const float4*)(srow + j8 * 8);
    const uint2 cv = *(const uint2*)(scode + j8 * 8);
    const _Float16* hp = (const _Float16*)&rv;
    const unsigned char* cb = (const unsigned char*)&cv;
#pragma unroll
    for (int k = 0; k < 8; ++k) {
      const int j = j8 * 8 + k;
      const float term = __logf(1.f + E * __expf(-(float)hp[k]));
      psum += (cb[k] == myc && j != i) ? term : 0.f;
    }
  }
#pragma unroll
  for (int off = 32; off; off >>= 1) psum += __shfl_down(psum, off);
  __syncthreads();
  if ((t & 63) == 0) red[t >> 6] = psum;
  __syncthreads();
  if (t == 0) {
    const float tot = red[0] + red[1] + red[2] + red[3];
    const int pos_cnt = cmy - 1;  // self is valid & same label
    float v;
    int fl;
    if (pos_cnt > 0) {
      v = tot / (float)pos_cnt;
      fl = 1;
    } else {
      v = __logf(1.f + E * __expf(-10.0f));  // logaddexp(1/T, lse) - 1/T
      fl = 0;
    }
    pa[i] = v;
    pflag[i] = fl;
  }
}

// ---------------- K4: final deterministic reduce ----------------------------
__global__ __launch_bounds__(256) void k_final(const float* __restrict__ pa,
                                               const int* __restrict__ pflag,
                                               float* __restrict__ out,
                                               int Nv) {
  const int t = threadIdx.x;
  double s = 0.0;
  int c = 0;
  for (int j = t; j < Nv; j += 256) {
    s += (double)pa[j];
    c += pflag[j];
  }
#pragma unroll
  for (int off = 32; off; off >>= 1) {
    s += __shfl_down(s, off);
    c += __shfl_down(c, off);
  }
  __shared__ double sd[4];
  __shared__ int si[4];
  if ((t & 63) == 0) {
    sd[t >> 6] = s;
    si[t >> 6] = c;
  }
  __syncthreads();
  if (t == 0) {
    const double st = sd[0] + sd[1] + sd[2] + sd[3];
    const int ct = 1 + si[0] + si[1] + si[2] + si[3];
    out[0] = (float)(st / (double)ct);
  }
}

extern "C" void kernel_launch(void* const* d_in, const int* in_sizes, int n_in,
                              void* d_out, int out_size, void* d_ws,
                              size_t ws_size, hipStream_t stream) {
  const float* X = (const float*)d_in[0];
  const int* labels = (const int*)d_in[1];
  const int* bad = (const int*)d_in[2];
  const int Nv = in_sizes[1];
  const int Dv = in_sizes[0] / Nv;

  size_t off = 0;
  auto alloc = [&](size_t bytes) -> void* {
    size_t p = (off + 255) & ~(size_t)255;
    off = p + bytes;
    return (void*)((char*)d_ws + p);
  };
  __bf16* fn = (__bf16*)alloc((size_t)Nv * Dv * 2);
  _Float16* S = (_Float16*)alloc((size_t)Nv * Nv * 2);
  float* pa = (float*)alloc((size_t)Nv * 4);
  int* pflag = (int*)alloc((size_t)Nv * 4);
  unsigned char* code = (unsigned char*)alloc((size_t)Nv);
  int* cntv = (int*)alloc(16);
  if (off > ws_size) return;  // scratch too small: fail loudly at validation

  k_init<<<1, 64, 0, stream>>>(cntv);
  k_normalize<<<Nv, 128, 0, stream>>>(X, labels, bad, fn, code, cntv, Dv);
  dim3 g(Nv / 128, Nv / 128);
  k_gemm<<<g, 256, 0, stream>>>(fn, S, Nv, Dv);
  k_rows<<<Nv, 256, 0, stream>>>(S, code, cntv, pa, pflag, Nv);
  k_final<<<1, 256, 0, stream>>>(pa, pflag, (float*)d_out, Nv);
}

// Round 3
// 224.650 us; speedup vs baseline: 1.1994x; 1.1900x over previous
//
#include <hip/hip_runtime.h>

typedef __bf16 bf16x8 __attribute__((ext_vector_type(8)));
typedef __bf16 bf16x4 __attribute__((ext_vector_type(4)));
typedef float f32x4 __attribute__((ext_vector_type(4)));
typedef _Float16 f16x4 __attribute__((ext_vector_type(4)));

#define GLOAD_LDS16(g, l)                                                      \
  __builtin_amdgcn_global_load_lds(                                            \
      (const __attribute__((address_space(1))) void*)(g),                      \
      (__attribute__((address_space(3))) void*)(l), 16, 0, 0)

// ---------------- K0: zero the label histogram ----------------
__global__ void k_init(int* __restrict__ cntv) {
  if (threadIdx.x < 4) cntv[threadIdx.x] = 0;
}

// ---------------- K1: normalize rows -> bf16, build code[] + histogram ------
__global__ __launch_bounds__(128) void k_normalize(
    const float* __restrict__ X, const int* __restrict__ labels,
    const int* __restrict__ bad, __bf16* __restrict__ fn,
    unsigned char* __restrict__ code, int* __restrict__ cntv, int Dv) {
  const int row = blockIdx.x;
  const int t = threadIdx.x;
  const float4* xr = (const float4*)(X + (size_t)row * Dv);
  float ss = 0.f;
  const int nv4 = Dv >> 2;
  for (int idx = t; idx < nv4; idx += 128) {
    float4 v = xr[idx];
    ss += v.x * v.x + v.y * v.y + v.z * v.z + v.w * v.w;
  }
#pragma unroll
  for (int off = 32; off; off >>= 1) ss += __shfl_down(ss, off);
  __shared__ float sred[2];
  if ((t & 63) == 0) sred[t >> 6] = ss;
  __syncthreads();
  const float inv = 1.0f / sqrtf(sred[0] + sred[1]);
  for (int idx = t; idx < nv4; idx += 128) {
    float4 v = xr[idx];
    bf16x4 o;
    o.x = (__bf16)(v.x * inv);
    o.y = (__bf16)(v.y * inv);
    o.z = (__bf16)(v.z * inv);
    o.w = (__bf16)(v.w * inv);
    *(bf16x4*)(fn + (size_t)row * Dv + idx * 4) = o;
  }
  if (t == 0) {
    const bool valid = (bad[row] == 0);
    unsigned char c = valid ? (unsigned char)labels[row] : (unsigned char)255;
    code[row] = c;
    if (valid) atomicAdd(&cntv[c], 1);
  }
}

// ---------------- K2: S = (fn . fn^T) * 10, fp16 out, SYMMETRIC half --------
// Triangular grid over 128x128 tiles (bi<=bj). BK=32 main loop (bank-friendly
// stride-64B LDS rows — BK=64's 128B stride halved bank utilization, R2).
// Off-diagonal tiles stored twice (normal + transposed) via 64x136 fp16 LDS
// strips unioned into the 32KB As/Bs space.
__global__ __launch_bounds__(256) void k_gemm(const __bf16* __restrict__ fn,
                                              _Float16* __restrict__ S, int Nv,
                                              int Dv) {
  __shared__ __align__(16) char smem[32768];
  __bf16* As = (__bf16*)smem;            // 128 x 32 bf16
  __bf16* Bs = (__bf16*)(smem + 16384);  // 128 x 32 bf16
  _Float16* Cs = (_Float16*)smem;        // 64 x 136 fp16 strip (epilogue)

  const int NT = Nv >> 7;
  int bi = 0, rem = blockIdx.x, span = NT;
  while (rem >= span) {
    rem -= span;
    bi++;
    span--;
  }
  const int bj = bi + rem;

  const int t = threadIdx.x;
  const int lane = t & 63;
  const int wave = t >> 6;
  const int quad = lane >> 4;
  const int l16 = lane & 15;
  const int wm = (wave >> 1) * 64;
  const int wn = (wave & 1) * 64;
  const size_t rowA = (size_t)bi * 128;
  const size_t rowB = (size_t)bj * 128;
  f32x4 acc[4][4] = {};

  for (int k0 = 0; k0 < Dv; k0 += 32) {
#pragma unroll
    for (int it = 0; it < 2; ++it) {
      const int c = t + it * 256;  // chunk 0..511 ; chunk = 16B = 8 bf16
      const int r = c >> 2;
      const int q = c & 3;
      const __bf16* ga = fn + (rowA + r) * Dv + k0 + q * 8;
      const __bf16* gb = fn + (rowB + r) * Dv + k0 + q * 8;
      // LDS dest is wave-uniform base + lane*16 (HW behavior)
      __bf16* la = As + (size_t)(it * 256 + wave * 64) * 8;
      __bf16* lb = Bs + (size_t)(it * 256 + wave * 64) * 8;
      GLOAD_LDS16(ga, la);
      GLOAD_LDS16(gb, lb);
    }
    __syncthreads();
    bf16x8 af[4], bfv[4];
#pragma unroll
    for (int mi = 0; mi < 4; ++mi)
      af[mi] = *(const bf16x8*)(As + (wm + mi * 16 + l16) * 32 + quad * 8);
#pragma unroll
    for (int ni = 0; ni < 4; ++ni)
      bfv[ni] = *(const bf16x8*)(Bs + (wn + ni * 16 + l16) * 32 + quad * 8);
#pragma unroll
    for (int mi = 0; mi < 4; ++mi)
#pragma unroll
      for (int ni = 0; ni < 4; ++ni)
        acc[mi][ni] = __builtin_amdgcn_mfma_f32_16x16x32_bf16(
            af[mi], bfv[ni], acc[mi][ni], 0, 0, 0);
    __syncthreads();
  }

  // C/D layout (verified m89/m91): col = lane&15, row = quad*4 + reg
  // Normal strips: rows [s*64, s*64+64) of the tile -> S[rowA+.., rowB+..]
#pragma unroll
  for (int s = 0; s < 2; ++s) {
    __syncthreads();
    if ((wave >> 1) == s) {
#pragma unroll
      for (int mi = 0; mi < 4; ++mi)
#pragma unroll
        for (int ni = 0; ni < 4; ++ni)
#pragma unroll
          for (int r = 0; r < 4; ++r)
            Cs[(mi * 16 + quad * 4 + r) * 136 + wn + ni * 16 + l16] =
                (_Float16)(acc[mi][ni][r] * 10.0f);
    }
    __syncthreads();
#pragma unroll
    for (int it = 0; it < 4; ++it) {
      const int idx = t + it * 256;  // 0..1023: row*16 + 16B-chunk
      const int row = idx >> 4;
      const int ch = idx & 15;
      *(float4*)(S + (rowA + s * 64 + row) * Nv + rowB + ch * 8) =
          *(const float4*)(Cs + row * 136 + ch * 8);
    }
  }
  if (bi == bj) return;
  // Mirror strips: rows of S^T tile = cols [s*64, s*64+64) of C.
  // Lane's 4 consecutive C-rows (quad*4+r) are contiguous in the mirror -> b64.
#pragma unroll
  for (int s = 0; s < 2; ++s) {
    __syncthreads();
    if ((wave & 1) == s) {
#pragma unroll
      for (int mi = 0; mi < 4; ++mi)
#pragma unroll
        for (int ni = 0; ni < 4; ++ni) {
          f16x4 v;
#pragma unroll
          for (int r = 0; r < 4; ++r) v[r] = (_Float16)(acc[mi][ni][r] * 10.0f);
          *(f16x4*)(Cs + (ni * 16 + l16) * 136 + wm + mi * 16 + quad * 4) = v;
        }
    }
    __syncthreads();
#pragma unroll
    for (int it = 0; it < 4; ++it) {
      const int idx = t + it * 256;
      const int row = idx >> 4;
      const int ch = idx & 15;
      *(float4*)(S + (rowB + s * 64 + row) * Nv + rowA + ch * 8) =
          *(const float4*)(Cs + row * 136 + ch * 8);
    }
  }
}

// ---------------- K3: per-row reductions (register-resident) ----------------
__global__ __launch_bounds__(256) void k_rows(
    const _Float16* __restrict__ S, const unsigned char* __restrict__ code,
    const int* __restrict__ cntv, float* __restrict__ pa,
    int* __restrict__ pflag, int Nv) {
  const int i = blockIdx.x;
  const int t = threadIdx.x;
  const int myc = code[i];
  const int c0 = cntv[0], c1 = cntv[1], c2 = cntv[2];
  const int validTotal = c0 + c1 + c2;
  if (myc > 2) {  // invalid anchor: not processed
    if (t == 0) { pa[i] = 0.f; pflag[i] = 0; }
    return;
  }
  const int cmy = (myc == 0) ? c0 : ((myc == 1) ? c1 : c2);
  if (validTotal - cmy == 0) {  // no negatives anywhere: not processed
    if (t == 0) { pa[i] = 0.f; pflag[i] = 0; }
    return;
  }
  // Each thread owns 4 chunks of 8 elements, held in registers for both passes.
  float4 xv[4];
  uint2 cv[4];
  {
    const float4* rp = (const float4*)(S + (size_t)i * Nv);
    const uint2* cp = (const uint2*)code;
#pragma unroll
    for (int k = 0; k < 4; ++k) {
      const int idx = t + k * 256;
      xv[k] = rp[idx];
      cv[k] = cp[idx];
    }
  }
  __shared__ float red[4];
  __shared__ float sE;
  // pass 1: E = sum over negatives of exp(S_ij). |S|<=~10: max ~8192*e^10
  // ~1.8e8, safely inside fp32 — no online max needed.
  float s = 0.f;
#pragma unroll
  for (int k = 0; k < 4; ++k) {
    const _Float16* hp = (const _Float16*)&xv[k];
    const unsigned char* cb = (const unsigned char*)&cv[k];
#pragma unroll
    for (int e = 0; e < 8; ++e) {
      const int cj = cb[e];
      const float ex = __expf((float)hp[e]);
      s += (cj <= 2 && cj != myc) ? ex : 0.f;
    }
  }
#pragma unroll
  for (int off = 32; off; off >>= 1) s += __shfl_down(s, off);
  if ((t & 63) == 0) red[t >> 6] = s;
  __syncthreads();
  if (t == 0) sE = red[0] + red[1] + red[2] + red[3];
  __syncthreads();
  const float E = sE;
  // pass 2: sum over positives of log1p(E * exp(-S_ij))
  float psum = 0.f;
#pragma unroll
  for (int k = 0; k < 4; ++k) {
    const _Float16* hp = (const _Float16*)&xv[k];
    const unsigned char* cb = (const unsigned char*)&cv[k];
#pragma unroll
    for (int e = 0; e < 8; ++e) {
      const int j = (t + k * 256) * 8 + e;
      const float term = __logf(1.f + E * __expf(-(float)hp[e]));
      psum += (cb[e] == myc && j != i) ? term : 0.f;
    }
  }
#pragma unroll
  for (int off = 32; off; off >>= 1) psum += __shfl_down(psum, off);
  __syncthreads();
  if ((t & 63) == 0) red[t >> 6] = psum;
  __syncthreads();
  if (t == 0) {
    const float tot = red[0] + red[1] + red[2] + red[3];
    const int pos_cnt = cmy - 1;  // self is valid & same label
    float v;
    int fl;
    if (pos_cnt > 0) {
      v = tot / (float)pos_cnt;
      fl = 1;
    } else {
      v = __logf(1.f + E * __expf(-10.0f));  // logaddexp(1/T, lse) - 1/T
      fl = 0;
    }
    pa[i] = v;
    pflag[i] = fl;
  }
}

// ---------------- K4: final deterministic reduce ----------------------------
__global__ __launch_bounds__(256) void k_final(const float* __restrict__ pa,
                                               const int* __restrict__ pflag,
                                               float* __restrict__ out,
                                               int Nv) {
  const int t = threadIdx.x;
  double s = 0.0;
  int c = 0;
  for (int j = t; j < Nv; j += 256) {
    s += (double)pa[j];
    c += pflag[j];
  }
#pragma unroll
  for (int off = 32; off; off >>= 1) {
    s += __shfl_down(s, off);
    c += __shfl_down(c, off);
  }
  __shared__ double sd[4];
  __shared__ int si[4];
  if ((t & 63) == 0) {
    sd[t >> 6] = s;
    si[t >> 6] = c;
  }
  __syncthreads();
  if (t == 0) {
    const double st = sd[0] + sd[1] + sd[2] + sd[3];
    const int ct = 1 + si[0] + si[1] + si[2] + si[3];
    out[0] = (float)(st / (double)ct);
  }
}

extern "C" void kernel_launch(void* const* d_in, const int* in_sizes, int n_in,
                              void* d_out, int out_size, void* d_ws,
                              size_t ws_size, hipStream_t stream) {
  const float* X = (const float*)d_in[0];
  const int* labels = (const int*)d_in[1];
  const int* bad = (const int*)d_in[2];
  const int Nv = in_sizes[1];
  const int Dv = in_sizes[0] / Nv;

  size_t off = 0;
  auto alloc = [&](size_t bytes) -> void* {
    size_t p = (off + 255) & ~(size_t)255;
    off = p + bytes;
    return (void*)((char*)d_ws + p);
  };
  __bf16* fn = (__bf16*)alloc((size_t)Nv * Dv * 2);
  _Float16* S = (_Float16*)alloc((size_t)Nv * Nv * 2);
  float* pa = (float*)alloc((size_t)Nv * 4);
  int* pflag = (int*)alloc((size_t)Nv * 4);
  unsigned char* code = (unsigned char*)alloc((size_t)Nv);
  int* cntv = (int*)alloc(16);
  if (off > ws_size) return;  // scratch too small: fail loudly at validation

  k_init<<<1, 64, 0, stream>>>(cntv);
  k_normalize<<<Nv, 128, 0, stream>>>(X, labels, bad, fn, code, cntv, Dv);
  const int NT = Nv / 128;
  k_gemm<<<NT * (NT + 1) / 2, 256, 0, stream>>>(fn, S, Nv, Dv);
  k_rows<<<Nv, 256, 0, stream>>>(S, code, cntv, pa, pflag, Nv);
  k_final<<<1, 256, 0, stream>>>(pa, pflag, (float*)d_out, Nv);
}